// Round 1
// baseline (2228.048 us; speedup 1.0000x reference)
//
#include <hip/hip_runtime.h>

// Problem constants
#define TOKS 100352   // BT*L = 32*3136
#define LDIM 3136     // H*W
#define SCALE_F 0.17677669529663687f  // 32^-0.5

typedef unsigned short u16;
typedef u16   u16x8 __attribute__((ext_vector_type(8)));
typedef float f32x8 __attribute__((ext_vector_type(8)));

__device__ __forceinline__ float bf2f(u16 u){ return __uint_as_float(((unsigned)u)<<16); }
__device__ __forceinline__ u16 f2bf(float f){
  unsigned u = __float_as_uint(f);
  return (u16)((u + 0x7FFFu + ((u>>16)&1u)) >> 16);   // RNE
}
__device__ __forceinline__ f32x8 ldbf8(const u16* p){
  u16x8 u = *(const u16x8*)p;
  f32x8 f;
  #pragma unroll
  for (int j=0;j<8;j++) f[j] = bf2f(u[j]);
  return f;
}
__device__ __forceinline__ float sum8(f32x8 a){
  return ((a[0]+a[1])+(a[2]+a[3]))+((a[4]+a[5])+(a[6]+a[7]));
}
__device__ __forceinline__ float gelu_f(float x){
  return 0.5f*x*(1.0f + erff(x*0.70710678118654752f));  // exact gelu
}
__device__ __forceinline__ void fma48(float (&acc)[4][8], float4 a, float4 b0, float4 b1){
  float ar[4] = {a.x,a.y,a.z,a.w};
  float br[8] = {b0.x,b0.y,b0.z,b0.w,b1.x,b1.y,b1.z,b1.w};
  #pragma unroll
  for (int i=0;i<4;i++){
    #pragma unroll
    for (int j=0;j<8;j++) acc[i][j] += ar[i]*br[j];
  }
}

// ---------------- LayerNorm: one wave per token (C=128) ----------------
__global__ __launch_bounds__(256) void ln_kernel(const float* __restrict__ x,
    const float* __restrict__ g, const float* __restrict__ bta, float* __restrict__ out)
{
  int tok  = (int)((blockIdx.x*256u + threadIdx.x) >> 6);
  int lane = threadIdx.x & 63;
  const float* xr = x + (size_t)tok*128;
  float v0 = xr[lane], v1 = xr[lane+64];
  float s = v0+v1;
  #pragma unroll
  for (int o=32;o;o>>=1) s += __shfl_xor(s,o);
  float m = s*(1.0f/128.0f);
  float d0=v0-m, d1=v1-m;
  float q = d0*d0+d1*d1;
  #pragma unroll
  for (int o=32;o;o>>=1) q += __shfl_xor(q,o);
  float rs = rsqrtf(q*(1.0f/128.0f)+1e-5f);
  float* orow = out + (size_t)tok*128;
  orow[lane]    = d0*rs*g[lane]   + bta[lane];
  orow[lane+64] = d1*rs*g[lane+64]+ bta[lane+64];
}

// ---- GEMM: (TOK,128)f32 @ (128,N)f32 + bias [-> optional gelu] -> bf16 ----
// grid (TOK/64, N/128), block 256. X staged transposed in LDS; W direct from global.
__global__ __launch_bounds__(256) void gemm_k128(
    const float* __restrict__ X, const float* __restrict__ W,
    const float* __restrict__ bias, u16* __restrict__ out,
    int N, int do_gelu)
{
  __shared__ float Xt[128][68];   // [k][r], pad 68 -> 16B-aligned rows, 2-way max
  const int tid = threadIdx.x;
  const size_t row0 = (size_t)blockIdx.x*64;
  const int col0 = blockIdx.y*128;
  #pragma unroll
  for (int i=0;i<32;i++){
    int idx = i*256+tid; int r = idx>>7, k = idx&127;
    Xt[k][r] = X[(row0+r)*128 + k];
  }
  __syncthreads();
  const int tx = tid&15, ty = tid>>4;
  const int r0 = ty*4;
  const int c0 = col0 + tx*4;
  float acc[4][8] = {};
  const float* Wc = W + c0;
  #pragma unroll 4
  for (int k=0;k<128;k++){
    float4 a  = *(const float4*)&Xt[k][r0];
    float4 b0 = *(const float4*)&Wc[(size_t)k*N];
    float4 b1v= *(const float4*)&Wc[(size_t)k*N + 64];
    fma48(acc, a, b0, b1v);
  }
  float bb[8];
  #pragma unroll
  for (int j=0;j<4;j++){ bb[j]=bias[c0+j]; bb[4+j]=bias[c0+64+j]; }
  #pragma unroll
  for (int i=0;i<4;i++){
    size_t r = row0+r0+i;
    float v[8];
    #pragma unroll
    for (int j=0;j<8;j++){
      float tv = acc[i][j]+bb[j];
      v[j] = do_gelu ? gelu_f(tv) : tv;
    }
    ushort4 pk0, pk1;
    pk0.x=f2bf(v[0]); pk0.y=f2bf(v[1]); pk0.z=f2bf(v[2]); pk0.w=f2bf(v[3]);
    pk1.x=f2bf(v[4]); pk1.y=f2bf(v[5]); pk1.z=f2bf(v[6]); pk1.w=f2bf(v[7]);
    *(ushort4*)&out[r*(size_t)N + c0]      = pk0;
    *(ushort4*)&out[r*(size_t)N + c0 + 64] = pk1;
  }
}

// ---------------- temporal attention (T=8 per (b,l), 4 heads) ----------------
// block: 8 l-positions x 4 heads x 8 t = 256 threads; grid = 4*392
__global__ __launch_bounds__(256) void t_attn_kernel(const u16* __restrict__ qkv,
    const float* __restrict__ tpb, float* __restrict__ o)
{
  const int tid = threadIdx.x;
  const int li = tid>>5, h = (tid>>3)&3, t = tid&7;
  const int b = blockIdx.x/392, lt = blockIdx.x%392;
  const int l = lt*8+li;
  const size_t rowt = (size_t)(b*8+t)*LDIM + l;
  const u16* qp = qkv + rowt*384 + h*32;
  f32x8 q0 = ldbf8(qp)   *SCALE_F, q1 = ldbf8(qp+8) *SCALE_F,
        q2 = ldbf8(qp+16)*SCALE_F, q3 = ldbf8(qp+24)*SCALE_F;
  float s[8];
  #pragma unroll
  for (int t2=0;t2<8;t2++){
    const u16* kp = qkv + ((size_t)(b*8+t2)*LDIM + l)*384 + 128 + h*32;
    f32x8 d = q0*ldbf8(kp) + q1*ldbf8(kp+8) + q2*ldbf8(kp+16) + q3*ldbf8(kp+24);
    s[t2] = sum8(d) + tpb[(t-t2+7)*4 + h];
  }
  float m = s[0];
  #pragma unroll
  for (int t2=1;t2<8;t2++) m = fmaxf(m, s[t2]);
  float ssum = 0.f;
  #pragma unroll
  for (int t2=0;t2<8;t2++){ s[t2] = __expf(s[t2]-m); ssum += s[t2]; }
  const float inv = 1.0f/ssum;
  f32x8 o0={0,0,0,0,0,0,0,0}, o1={0,0,0,0,0,0,0,0},
        o2={0,0,0,0,0,0,0,0}, o3={0,0,0,0,0,0,0,0};
  #pragma unroll
  for (int t2=0;t2<8;t2++){
    const u16* vp = qkv + ((size_t)(b*8+t2)*LDIM + l)*384 + 256 + h*32;
    float aw = s[t2]*inv;
    o0 += aw*ldbf8(vp); o1 += aw*ldbf8(vp+8); o2 += aw*ldbf8(vp+16); o3 += aw*ldbf8(vp+24);
  }
  float* op = o + rowt*128 + h*32;
  *(f32x8*)op = o0; *(f32x8*)(op+8) = o1; *(f32x8*)(op+16) = o2; *(f32x8*)(op+24) = o3;
}

// --------- shifted-window spatial attention: block per (bt,wh,ww), wave per head ---------
// Roll/window/mask folded into index math. lane = query index (49 active), online exp.
__global__ __launch_bounds__(256) void s_attn_kernel(const u16* __restrict__ qkv,
    const float* __restrict__ rpb, float* __restrict__ o)
{
  __shared__ int rowL[49];
  __shared__ int codeL[49];
  const int tid = threadIdx.x;
  const int bidx = blockIdx.x;
  const int bt = bidx>>6, wh = (bidx>>3)&7, ww = bidx&7;
  if (tid < 49){
    int ph = tid/7, pwv = tid%7;
    int rh = wh*7+ph, rw = ww*7+pwv;
    int oh = rh+3; if (oh>=56) oh-=56;   // roll(-3): rolled[rh] = x[(rh+3)%56]
    int ow = rw+3; if (ow>=56) ow-=56;
    rowL[tid] = bt*LDIM + oh*56 + ow;
    int chh = (rh<49)?0:((rh<53)?1:2);   // Swin shift-mask region codes
    int cww = (rw<49)?0:((rw<53)?1:2);
    codeL[tid] = chh*3+cww;
  }
  __syncthreads();
  const int h = tid>>6;
  const int lane = tid&63;
  const int i = (lane<49)?lane:0;
  const int myrow = rowL[i];
  const int ci = codeL[i];
  const int ih = i/7, iw = i%7;
  const u16* qp = qkv + (size_t)myrow*384 + h*32;
  f32x8 q0 = ldbf8(qp)   *SCALE_F, q1 = ldbf8(qp+8) *SCALE_F,
        q2 = ldbf8(qp+16)*SCALE_F, q3 = ldbf8(qp+24)*SCALE_F;
  f32x8 o0={0,0,0,0,0,0,0,0}, o1={0,0,0,0,0,0,0,0},
        o2={0,0,0,0,0,0,0,0}, o3={0,0,0,0,0,0,0,0};
  float ssum = 0.f;
  for (int jh=0;jh<7;jh++){
    #pragma unroll
    for (int jw=0;jw<7;jw++){
      const int j = jh*7+jw;
      const int rj = rowL[j];
      const u16* kp = qkv + (size_t)rj*384 + 128 + h*32;
      f32x8 d8 = q0*ldbf8(kp)+q1*ldbf8(kp+8)+q2*ldbf8(kp+16)+q3*ldbf8(kp+24);
      float s = sum8(d8);
      s += rpb[((ih-jh+6)*13 + (iw-jw+6))*4 + h];
      if (ci != codeL[j]) s -= 100.0f;
      float p = __expf(s);         // |s|<=~1 unmasked; masked -> exp(-100)=0
      ssum += p;
      const u16* vp = qkv + (size_t)rj*384 + 256 + h*32;
      o0 += p*ldbf8(vp); o1 += p*ldbf8(vp+8); o2 += p*ldbf8(vp+16); o3 += p*ldbf8(vp+24);
    }
  }
  if (lane < 49){
    const float inv = 1.0f/ssum;
    float* op = o + (size_t)myrow*128 + h*32;
    *(f32x8*)op = o0*inv; *(f32x8*)(op+8) = o1*inv;
    *(f32x8*)(op+16) = o2*inv; *(f32x8*)(op+24) = o3*inv;
  }
}

// ---- proj + adapter + residual: out = xres + smode*p + A2(gelu(A1(p))), p = o@pw+pb ----
// 64-token tile, grid TOK/64. sT holds o^T then p^T (aliased, barrier-separated).
__global__ __launch_bounds__(256) void proj_adapter_kernel(
    const float* __restrict__ o, const float* __restrict__ xres,
    const float* __restrict__ pw, const float* __restrict__ pb,
    const float* __restrict__ w1, const float* __restrict__ b1,
    const float* __restrict__ w2, const float* __restrict__ b2,
    float* __restrict__ out, int smode)
{
  __shared__ float sT[128][68];   // o^T, then p^T
  __shared__ float hT[32][68];
  const int tid = threadIdx.x;
  const size_t row0 = (size_t)blockIdx.x*64;
  #pragma unroll
  for (int i=0;i<32;i++){
    int idx = i*256+tid; int r = idx>>7, k = idx&127;
    sT[k][r] = o[(row0+r)*128 + k];
  }
  __syncthreads();
  const int tx = tid&15, ty = tid>>4;
  const int r0 = ty*4;
  float acc[4][8] = {};
  {
    const float* Wc = pw + tx*4;
    #pragma unroll 4
    for (int k=0;k<128;k++){
      float4 a  = *(const float4*)&sT[k][r0];
      float4 b0 = *(const float4*)&Wc[k*128];
      float4 b1v= *(const float4*)&Wc[k*128+64];
      fma48(acc, a, b0, b1v);
    }
  }
  __syncthreads();   // all reads of o^T done; safe to overwrite with p^T
  {
    float bb[8];
    #pragma unroll
    for (int j=0;j<4;j++){ bb[j]=pb[tx*4+j]; bb[4+j]=pb[64+tx*4+j]; }
    #pragma unroll
    for (int i=0;i<4;i++){
      #pragma unroll
      for (int j=0;j<4;j++){
        sT[tx*4+j][r0+i]    = acc[i][j]   + bb[j];
        sT[64+tx*4+j][r0+i] = acc[i][4+j] + bb[4+j];
      }
    }
  }
  __syncthreads();
  {  // h = gelu(p @ w1 + b1): thread (j in 0..31, tg in 0..7) -> tokens tg*8..+7
    int j = tid&31, tg = tid>>5;
    float hacc[8] = {};
    #pragma unroll 2
    for (int k=0;k<128;k++){
      float w = w1[k*32 + j];
      float4 p0 = *(const float4*)&sT[k][tg*8];
      float4 p1 = *(const float4*)&sT[k][tg*8+4];
      hacc[0]+=p0.x*w; hacc[1]+=p0.y*w; hacc[2]+=p0.z*w; hacc[3]+=p0.w*w;
      hacc[4]+=p1.x*w; hacc[5]+=p1.y*w; hacc[6]+=p1.z*w; hacc[7]+=p1.w*w;
    }
    float bj = b1[j];
    #pragma unroll
    for (int p=0;p<8;p++) hT[j][tg*8+p] = gelu_f(hacc[p]+bj);
  }
  __syncthreads();
  {  // a = h @ w2 + b2; out = xres + smode*p + a
    float acc2[4][8] = {};
    const float* Wc = w2 + tx*4;
    #pragma unroll
    for (int k=0;k<32;k++){
      float4 a  = *(const float4*)&hT[k][r0];
      float4 b0 = *(const float4*)&Wc[k*128];
      float4 b1v= *(const float4*)&Wc[k*128+64];
      fma48(acc2, a, b0, b1v);
    }
    float bb[8];
    #pragma unroll
    for (int j=0;j<4;j++){ bb[j]=b2[tx*4+j]; bb[4+j]=b2[64+tx*4+j]; }
    #pragma unroll
    for (int i=0;i<4;i++){
      size_t r = row0 + r0 + i;
      float4 x0 = *(const float4*)&xres[r*128 + tx*4];
      float4 x1 = *(const float4*)&xres[r*128 + 64 + tx*4];
      float xa[8] = {x0.x,x0.y,x0.z,x0.w,x1.x,x1.y,x1.z,x1.w};
      float v[8];
      #pragma unroll
      for (int j=0;j<8;j++){
        float pres = 0.0f;
        if (smode){
          int cc = (j<4) ? (tx*4+j) : (64+tx*4+(j-4));
          pres = sT[cc][r0+i];
        }
        v[j] = xa[j] + acc2[i][j] + bb[j] + pres;
      }
      *(float4*)&out[r*128 + tx*4]      = make_float4(v[0],v[1],v[2],v[3]);
      *(float4*)&out[r*128 + 64 + tx*4] = make_float4(v[4],v[5],v[6],v[7]);
    }
  }
}

// ---------------- AIM adapter branch: ada = gelu(xn@w1+b1)@w2 + b2 ----------------
__global__ __launch_bounds__(256) void adapter_kernel(
    const float* __restrict__ xn,
    const float* __restrict__ w1, const float* __restrict__ b1,
    const float* __restrict__ w2, const float* __restrict__ b2,
    float* __restrict__ ada)
{
  __shared__ float xT[128][68];
  __shared__ float hT[32][68];
  const int tid = threadIdx.x;
  const size_t row0 = (size_t)blockIdx.x*64;
  #pragma unroll
  for (int i=0;i<32;i++){
    int idx = i*256+tid; int r = idx>>7, k = idx&127;
    xT[k][r] = xn[(row0+r)*128 + k];
  }
  __syncthreads();
  {
    int j = tid&31, tg = tid>>5;
    float hacc[8] = {};
    #pragma unroll 2
    for (int k=0;k<128;k++){
      float w = w1[k*32 + j];
      float4 p0 = *(const float4*)&xT[k][tg*8];
      float4 p1 = *(const float4*)&xT[k][tg*8+4];
      hacc[0]+=p0.x*w; hacc[1]+=p0.y*w; hacc[2]+=p0.z*w; hacc[3]+=p0.w*w;
      hacc[4]+=p1.x*w; hacc[5]+=p1.y*w; hacc[6]+=p1.z*w; hacc[7]+=p1.w*w;
    }
    float bj = b1[j];
    #pragma unroll
    for (int p=0;p<8;p++) hT[j][tg*8+p] = gelu_f(hacc[p]+bj);
  }
  __syncthreads();
  {
    const int tx = tid&15, ty = tid>>4;
    const int r0 = ty*4;
    float acc2[4][8] = {};
    const float* Wc = w2 + tx*4;
    #pragma unroll
    for (int k=0;k<32;k++){
      float4 a  = *(const float4*)&hT[k][r0];
      float4 b0 = *(const float4*)&Wc[k*128];
      float4 b1v= *(const float4*)&Wc[k*128+64];
      fma48(acc2, a, b0, b1v);
    }
    float bb[8];
    #pragma unroll
    for (int j=0;j<4;j++){ bb[j]=b2[tx*4+j]; bb[4+j]=b2[64+tx*4+j]; }
    #pragma unroll
    for (int i=0;i<4;i++){
      size_t r = row0 + r0 + i;
      *(float4*)&ada[r*128 + tx*4] =
        make_float4(acc2[i][0]+bb[0],acc2[i][1]+bb[1],acc2[i][2]+bb[2],acc2[i][3]+bb[3]);
      *(float4*)&ada[r*128 + 64 + tx*4] =
        make_float4(acc2[i][4]+bb[4],acc2[i][5]+bb[5],acc2[i][6]+bb[6],acc2[i][7]+bb[7]);
    }
  }
}

// ------- MLP second GEMM: out = out + Hb(bf16)@W2 + b2 + 0.5*ada (in-place on d_out) -------
__global__ __launch_bounds__(256) void mlp_gemm2_kernel(
    const u16* __restrict__ Hb, const float* __restrict__ W2,
    const float* __restrict__ b2, const float* __restrict__ ada,
    float* __restrict__ out)
{
  __shared__ float Xt[64][68];
  const int tid = threadIdx.x;
  const size_t row0 = (size_t)blockIdx.x*64;
  const int tx = tid&15, ty = tid>>4;
  const int r0 = ty*4;
  float acc[4][8] = {};
  for (int kc=0;kc<512;kc+=64){
    #pragma unroll
    for (int i=0;i<16;i++){
      int idx = i*256+tid; int r = idx>>6, kk = idx&63;
      Xt[kk][r] = bf2f(Hb[(row0+r)*512 + kc + kk]);
    }
    __syncthreads();
    const float* Wc = W2 + (size_t)kc*128 + tx*4;
    #pragma unroll 4
    for (int k=0;k<64;k++){
      float4 a  = *(const float4*)&Xt[k][r0];
      float4 b0 = *(const float4*)&Wc[k*128];
      float4 b1v= *(const float4*)&Wc[k*128+64];
      fma48(acc, a, b0, b1v);
    }
    __syncthreads();   // protect Xt before next chunk's load
  }
  float bb[8];
  #pragma unroll
  for (int j=0;j<4;j++){ bb[j]=b2[tx*4+j]; bb[4+j]=b2[64+tx*4+j]; }
  #pragma unroll
  for (int i=0;i<4;i++){
    size_t r = row0+r0+i;
    float4 u0 = *(const float4*)&out[r*128+tx*4];
    float4 u1 = *(const float4*)&out[r*128+64+tx*4];
    float4 d0 = *(const float4*)&ada[r*128+tx*4];
    float4 d1 = *(const float4*)&ada[r*128+64+tx*4];
    float ua[8]={u0.x,u0.y,u0.z,u0.w,u1.x,u1.y,u1.z,u1.w};
    float da[8]={d0.x,d0.y,d0.z,d0.w,d1.x,d1.y,d1.z,d1.w};
    float v[8];
    #pragma unroll
    for (int j=0;j<8;j++) v[j] = ua[j] + acc[i][j] + bb[j] + 0.5f*da[j];
    *(float4*)&out[r*128+tx*4]    = make_float4(v[0],v[1],v[2],v[3]);
    *(float4*)&out[r*128+64+tx*4] = make_float4(v[4],v[5],v[6],v[7]);
  }
}

extern "C" void kernel_launch(void* const* d_in, const int* in_sizes, int n_in,
                              void* d_out, int out_size, void* d_ws, size_t ws_size,
                              hipStream_t stream)
{
  (void)in_sizes; (void)n_in; (void)out_size; (void)ws_size;
  const float* x      = (const float*)d_in[0];
  const float* qkv_w  = (const float*)d_in[1];
  const float* qkv_b  = (const float*)d_in[2];
  const float* proj_w = (const float*)d_in[3];
  const float* proj_b = (const float*)d_in[4];
  const float* rpb    = (const float*)d_in[5];
  const float* tpb    = (const float*)d_in[6];
  const float* n1g    = (const float*)d_in[7];
  const float* n1b    = (const float*)d_in[8];
  const float* n2g    = (const float*)d_in[9];
  const float* n2b    = (const float*)d_in[10];
  const float* mw1    = (const float*)d_in[11];
  const float* mb1    = (const float*)d_in[12];
  const float* mw2    = (const float*)d_in[13];
  const float* mb2    = (const float*)d_in[14];
  const float* sw1    = (const float*)d_in[15];
  const float* sb1    = (const float*)d_in[16];
  const float* sw2    = (const float*)d_in[17];
  const float* sb2    = (const float*)d_in[18];
  const float* tw1    = (const float*)d_in[19];
  const float* tb1    = (const float*)d_in[20];
  const float* tw2    = (const float*)d_in[21];
  const float* tb2    = (const float*)d_in[22];
  const float* aw1    = (const float*)d_in[23];
  const float* ab1    = (const float*)d_in[24];
  const float* aw2    = (const float*)d_in[25];
  const float* ab2    = (const float*)d_in[26];

  char* ws = (char*)d_ws;
  float* A  = (float*)ws;                              // 100352*128 f32  (xn / attn-out)
  u16*   Bq = (u16*)(ws + 51380224);                   // 100352*512 bf16 (qkv / mlp hidden)
  float* Cb = (float*)(ws + 51380224 + 102760448);     // 100352*128 f32  (x1 / ada)
  float* out = (float*)d_out;                          // x2, then final

  // ---- temporal attention + T_Adapter ----
  ln_kernel<<<25088,256,0,stream>>>(x, n1g, n1b, A);
  gemm_k128<<<dim3(1568,3),256,0,stream>>>(A, qkv_w, qkv_b, Bq, 384, 0);
  t_attn_kernel<<<1568,256,0,stream>>>(Bq, tpb, A);
  proj_adapter_kernel<<<1568,256,0,stream>>>(A, x, proj_w, proj_b, tw1, tb1, tw2, tb2, Cb, 0);
  // ---- shifted-window spatial attention + S_Adapter ----
  ln_kernel<<<25088,256,0,stream>>>(Cb, n1g, n1b, A);
  gemm_k128<<<dim3(1568,3),256,0,stream>>>(A, qkv_w, qkv_b, Bq, 384, 0);
  s_attn_kernel<<<2048,256,0,stream>>>(Bq, rpb, A);
  proj_adapter_kernel<<<1568,256,0,stream>>>(A, Cb, proj_w, proj_b, sw1, sb1, sw2, sb2, out, 1);
  // ---- MLP + MLP_Adapter ----
  ln_kernel<<<25088,256,0,stream>>>(out, n2g, n2b, A);
  adapter_kernel<<<1568,256,0,stream>>>(A, aw1, ab1, aw2, ab2, Cb);
  gemm_k128<<<dim3(1568,4),256,0,stream>>>(A, mw1, mb1, Bq, 512, 1);
  mlp_gemm2_kernel<<<1568,256,0,stream>>>(Bq, mw2, mb2, Cb, out);
}

// Round 2
// 921.710 us; speedup vs baseline: 2.4173x; 2.4173x over previous
//
#include <hip/hip_runtime.h>

#define TOKS 100352   // BT*L = 32*3136
#define LDIM 3136     // H*W
#define SCALE_F 0.17677669529663687f  // 32^-0.5

typedef unsigned short u16;
typedef u16   u16x8 __attribute__((ext_vector_type(8)));
typedef short s16x8 __attribute__((ext_vector_type(8)));
typedef float f32x8 __attribute__((ext_vector_type(8)));
typedef float f32x4 __attribute__((ext_vector_type(4)));

__device__ __forceinline__ float bf2f(u16 u){ return __uint_as_float(((unsigned)u)<<16); }
__device__ __forceinline__ u16 f2bf(float f){
  unsigned u = __float_as_uint(f);
  return (u16)((u + 0x7FFFu + ((u>>16)&1u)) >> 16);   // RNE
}
__device__ __forceinline__ f32x8 ldbf8(const u16* p){
  u16x8 u = *(const u16x8*)p;
  f32x8 f;
  #pragma unroll
  for (int j=0;j<8;j++) f[j] = bf2f(u[j]);
  return f;
}
__device__ __forceinline__ u16x8 pack8(f32x8 v){
  u16x8 r;
  #pragma unroll
  for (int j=0;j<8;j++) r[j] = f2bf(v[j]);
  return r;
}
__device__ __forceinline__ float sum8(f32x8 a){
  return ((a[0]+a[1])+(a[2]+a[3]))+((a[4]+a[5])+(a[6]+a[7]));
}
__device__ __forceinline__ float gelu_f(float x){
  return 0.5f*x*(1.0f + erff(x*0.70710678118654752f));  // exact gelu
}

// ---------------- weight prep: f32 (K,N) -> bf16 transposed (N,K) ----------------
struct WSrc { const float* p[10]; };
__global__ __launch_bounds__(256) void prep_w(WSrc s, u16* __restrict__ dst){
  const int Ks[10]={128,128,128,512,128,32,128,32,128,32};
  const int Ns[10]={384,128,512,128,32,128,32,128,32,128};
  const int off[11]={0,49152,65536,131072,196608,200704,204800,208896,212992,217088,221184};
  int idx = blockIdx.x*256+threadIdx.x;
  int m=0;
  #pragma unroll
  for (int i=0;i<10;i++) if (idx>=off[i+1]) m=i+1;
  int e = idx-off[m];
  int K=Ks[m], Nn=Ns[m];
  int n=e/K, k=e-n*K;
  dst[idx] = f2bf(s.p[m][k*Nn+n]);
}

// ---------------- LayerNorm: one wave per token (C=128), bf16 out ----------------
__global__ __launch_bounds__(256) void ln_kernel(const float* __restrict__ x,
    const float* __restrict__ g, const float* __restrict__ bta, u16* __restrict__ out)
{
  int tok  = (int)((blockIdx.x*256u + threadIdx.x) >> 6);
  int lane = threadIdx.x & 63;
  const float* xr = x + (size_t)tok*128;
  float v0 = xr[lane], v1 = xr[lane+64];
  float s = v0+v1;
  #pragma unroll
  for (int o=32;o;o>>=1) s += __shfl_xor(s,o);
  float m = s*(1.0f/128.0f);
  float d0=v0-m, d1=v1-m;
  float q = d0*d0+d1*d1;
  #pragma unroll
  for (int o=32;o;o>>=1) q += __shfl_xor(q,o);
  float rs = rsqrtf(q*(1.0f/128.0f)+1e-5f);
  u16* orow = out + (size_t)tok*128;
  orow[lane]    = f2bf(d0*rs*g[lane]   + bta[lane]);
  orow[lane+64] = f2bf(d1*rs*g[lane+64]+ bta[lane+64]);
}

// ---- MFMA GEMM: (TOKS,K)bf16 @ WT(N,K)bf16 -> out, per-wave 16 tok x NT*16 cols ----
// A frag: lane l -> X[m0+(l&15)][kt*32+(l>>4)*8 ..+7]; B frag: WT[n][same k] (D = A·B^T form)
// C/D: col=lane&15, row=(lane>>4)*4+reg  [HW-verified]
// EPI: 0=bf16 bias, 1=bf16 bias+gelu, 2=f32 bias+res1, 3=f32 bias+res1+resbf,
//      4=f32 bias+res1+0.5*ada (in-place safe), 5=f32 bias only
template<int KT, int NT, int EPI>
__global__ __launch_bounds__(256) void gemm_mfma(
    const u16* __restrict__ X, const u16* __restrict__ WT,
    const float* __restrict__ bias, void* outp, int N,
    const float* res1, const u16* __restrict__ resbf, const float* __restrict__ ada)
{
  constexpr int K = KT*32;
  const int tid = threadIdx.x;
  const int wv = tid>>6, lane = tid&63;
  const int lr = lane>>4, lc = lane&15;
  const size_t m0 = (size_t)blockIdx.x*64 + wv*16;
  const int n0 = blockIdx.y*(NT*16);
  f32x4 acc[NT];
  #pragma unroll
  for (int nt=0;nt<NT;nt++) acc[nt] = (f32x4){0.f,0.f,0.f,0.f};
  const u16* xa = X + (m0 + lc)*K + lr*8;
  const u16* wb = WT + ((size_t)(n0+lc))*K + lr*8;
  #pragma unroll 4
  for (int kt=0; kt<KT; kt++){
    s16x8 a = *(const s16x8*)(xa + kt*32);
    #pragma unroll
    for (int nt=0; nt<NT; nt++){
      s16x8 b = *(const s16x8*)(wb + (size_t)nt*16*K + kt*32);
      acc[nt] = __builtin_amdgcn_mfma_f32_16x16x32_bf16(a, b, acc[nt], 0,0,0);
    }
  }
  const int rowl = lr*4;
  #pragma unroll
  for (int nt=0; nt<NT; nt++){
    const int col = n0 + nt*16 + lc;
    const float bv = bias[col];
    #pragma unroll
    for (int r=0;r<4;r++){
      const size_t row = m0 + rowl + r;
      float v = acc[nt][r] + bv;
      if constexpr (EPI==1) v = gelu_f(v);
      if constexpr (EPI==0 || EPI==1){
        ((u16*)outp)[row*(size_t)N + col] = f2bf(v);
      } else {
        if constexpr (EPI==2) v += res1[row*128+col];
        if constexpr (EPI==3) v += res1[row*128+col] + bf2f(resbf[row*128+col]);
        if constexpr (EPI==4) v += res1[row*128+col] + 0.5f*ada[row*128+col];
        ((float*)outp)[row*128 + col] = v;
      }
    }
  }
}

// ---------------- temporal attention (T=8 per (b,l), 4 heads), bf16 out ----------------
__global__ __launch_bounds__(256) void t_attn_kernel(const u16* __restrict__ qkv,
    const float* __restrict__ tpb, u16* __restrict__ o)
{
  const int tid = threadIdx.x;
  const int li = tid>>5, h = (tid>>3)&3, t = tid&7;
  const int b = blockIdx.x/392, lt = blockIdx.x%392;
  const int l = lt*8+li;
  const size_t rowt = (size_t)(b*8+t)*LDIM + l;
  const u16* qp = qkv + rowt*384 + h*32;
  f32x8 q0 = ldbf8(qp)   *SCALE_F, q1 = ldbf8(qp+8) *SCALE_F,
        q2 = ldbf8(qp+16)*SCALE_F, q3 = ldbf8(qp+24)*SCALE_F;
  float s[8];
  #pragma unroll
  for (int t2=0;t2<8;t2++){
    const u16* kp = qkv + ((size_t)(b*8+t2)*LDIM + l)*384 + 128 + h*32;
    f32x8 d = q0*ldbf8(kp) + q1*ldbf8(kp+8) + q2*ldbf8(kp+16) + q3*ldbf8(kp+24);
    s[t2] = sum8(d) + tpb[(t-t2+7)*4 + h];
  }
  float m = s[0];
  #pragma unroll
  for (int t2=1;t2<8;t2++) m = fmaxf(m, s[t2]);
  float ssum = 0.f;
  #pragma unroll
  for (int t2=0;t2<8;t2++){ s[t2] = __expf(s[t2]-m); ssum += s[t2]; }
  const float inv = 1.0f/ssum;
  f32x8 o0={0,0,0,0,0,0,0,0}, o1={0,0,0,0,0,0,0,0},
        o2={0,0,0,0,0,0,0,0}, o3={0,0,0,0,0,0,0,0};
  #pragma unroll
  for (int t2=0;t2<8;t2++){
    const u16* vp = qkv + ((size_t)(b*8+t2)*LDIM + l)*384 + 256 + h*32;
    float aw = s[t2]*inv;
    o0 += aw*ldbf8(vp); o1 += aw*ldbf8(vp+8); o2 += aw*ldbf8(vp+16); o3 += aw*ldbf8(vp+24);
  }
  u16* op = o + rowt*128 + h*32;
  *(u16x8*)op      = pack8(o0); *(u16x8*)(op+8)  = pack8(o1);
  *(u16x8*)(op+16) = pack8(o2); *(u16x8*)(op+24) = pack8(o3);
}

// --------- shifted-window spatial attention, bf16 out ---------
__global__ __launch_bounds__(256) void s_attn_kernel(const u16* __restrict__ qkv,
    const float* __restrict__ rpb, u16* __restrict__ o)
{
  __shared__ int rowL[49];
  __shared__ int codeL[49];
  const int tid = threadIdx.x;
  const int bidx = blockIdx.x;
  const int bt = bidx>>6, wh = (bidx>>3)&7, ww = bidx&7;
  if (tid < 49){
    int ph = tid/7, pwv = tid%7;
    int rh = wh*7+ph, rw = ww*7+pwv;
    int oh = rh+3; if (oh>=56) oh-=56;   // roll(-3)
    int ow = rw+3; if (ow>=56) ow-=56;
    rowL[tid] = bt*LDIM + oh*56 + ow;
    int chh = (rh<49)?0:((rh<53)?1:2);
    int cww = (rw<49)?0:((rw<53)?1:2);
    codeL[tid] = chh*3+cww;
  }
  __syncthreads();
  const int h = tid>>6;
  const int lane = tid&63;
  const int i = (lane<49)?lane:0;
  const int myrow = rowL[i];
  const int ci = codeL[i];
  const int ih = i/7, iw = i%7;
  const u16* qp = qkv + (size_t)myrow*384 + h*32;
  f32x8 q0 = ldbf8(qp)   *SCALE_F, q1 = ldbf8(qp+8) *SCALE_F,
        q2 = ldbf8(qp+16)*SCALE_F, q3 = ldbf8(qp+24)*SCALE_F;
  f32x8 o0={0,0,0,0,0,0,0,0}, o1={0,0,0,0,0,0,0,0},
        o2={0,0,0,0,0,0,0,0}, o3={0,0,0,0,0,0,0,0};
  float ssum = 0.f;
  for (int jh=0;jh<7;jh++){
    #pragma unroll
    for (int jw=0;jw<7;jw++){
      const int j = jh*7+jw;
      const int rj = rowL[j];
      const u16* kp = qkv + (size_t)rj*384 + 128 + h*32;
      f32x8 d8 = q0*ldbf8(kp)+q1*ldbf8(kp+8)+q2*ldbf8(kp+16)+q3*ldbf8(kp+24);
      float s = sum8(d8);
      s += rpb[((ih-jh+6)*13 + (iw-jw+6))*4 + h];
      if (ci != codeL[j]) s -= 100.0f;
      float p = __expf(s);
      ssum += p;
      const u16* vp = qkv + (size_t)rj*384 + 256 + h*32;
      o0 += p*ldbf8(vp); o1 += p*ldbf8(vp+8); o2 += p*ldbf8(vp+16); o3 += p*ldbf8(vp+24);
    }
  }
  if (lane < 49){
    const float inv = 1.0f/ssum;
    u16* op = o + (size_t)myrow*128 + h*32;
    *(u16x8*)op      = pack8(o0*inv); *(u16x8*)(op+8)  = pack8(o1*inv);
    *(u16x8*)(op+16) = pack8(o2*inv); *(u16x8*)(op+24) = pack8(o3*inv);
  }
}

extern "C" void kernel_launch(void* const* d_in, const int* in_sizes, int n_in,
                              void* d_out, int out_size, void* d_ws, size_t ws_size,
                              hipStream_t stream)
{
  (void)in_sizes; (void)n_in; (void)out_size; (void)ws_size;
  const float* x      = (const float*)d_in[0];
  const float* qkv_w  = (const float*)d_in[1];
  const float* qkv_b  = (const float*)d_in[2];
  const float* proj_w = (const float*)d_in[3];
  const float* proj_b = (const float*)d_in[4];
  const float* rpb    = (const float*)d_in[5];
  const float* tpb    = (const float*)d_in[6];
  const float* n1g    = (const float*)d_in[7];
  const float* n1b    = (const float*)d_in[8];
  const float* n2g    = (const float*)d_in[9];
  const float* n2b    = (const float*)d_in[10];
  const float* mw1    = (const float*)d_in[11];
  const float* mb1    = (const float*)d_in[12];
  const float* mw2    = (const float*)d_in[13];
  const float* mb2    = (const float*)d_in[14];
  const float* sw1    = (const float*)d_in[15];
  const float* sb1    = (const float*)d_in[16];
  const float* sw2    = (const float*)d_in[17];
  const float* sb2    = (const float*)d_in[18];
  const float* tw1    = (const float*)d_in[19];
  const float* tb1    = (const float*)d_in[20];
  const float* tw2    = (const float*)d_in[21];
  const float* tb2    = (const float*)d_in[22];
  const float* aw1    = (const float*)d_in[23];
  const float* ab1    = (const float*)d_in[24];
  const float* aw2    = (const float*)d_in[25];
  const float* ab2    = (const float*)d_in[26];

  // workspace map (bytes):
  //   [0, 25.69M)      Xn (bf16 100352x128)  -- aliased with P (disjoint lifetimes)
  //   [25.69M,128.45M) QKV (bf16 100352x384) / MLP-H (100352x512); O at +77.07M
  //   [128.45M,134.87M) Hq (bf16 100352x32)
  //   [134.87M,186.25M) Cb (f32 100352x128): X1 then ADA
  //   [186.25M,186.70M) WT (bf16 transposed weights, 221184 elems)
  char* ws = (char*)d_ws;
  u16*   Xn  = (u16*)(ws);
  u16*   P   = Xn;                           // alias; timeline-verified disjoint
  u16*   QKV = (u16*)(ws + 25690112ULL);     // also MLP hidden H
  u16*   O   = (u16*)(ws + 102760448ULL);
  u16*   Hq  = (u16*)(ws + 128450560ULL);
  float* Cb  = (float*)(ws + 134873088ULL);
  u16*   WT  = (u16*)(ws + 186253312ULL);
  float* out = (float*)d_out;

  const u16 *WTqkv=WT, *WTproj=WT+49152, *WTm1=WT+65536, *WTm2=WT+131072,
            *WTt1=WT+196608, *WTt2=WT+200704, *WTs1=WT+204800, *WTs2=WT+208896,
            *WTa1=WT+212992, *WTa2=WT+217088;

  WSrc srcs; srcs.p[0]=qkv_w; srcs.p[1]=proj_w; srcs.p[2]=mw1; srcs.p[3]=mw2;
  srcs.p[4]=tw1; srcs.p[5]=tw2; srcs.p[6]=sw1; srcs.p[7]=sw2; srcs.p[8]=aw1; srcs.p[9]=aw2;
  prep_w<<<864,256,0,stream>>>(srcs, WT);

  // ---- temporal attention + T_Adapter ----
  ln_kernel<<<25088,256,0,stream>>>(x, n1g, n1b, Xn);
  gemm_mfma<4,4,0><<<dim3(1568,6),256,0,stream>>>(Xn, WTqkv, qkv_b, QKV, 384, nullptr,nullptr,nullptr);
  t_attn_kernel<<<1568,256,0,stream>>>(QKV, tpb, O);
  gemm_mfma<4,4,0><<<dim3(1568,2),256,0,stream>>>(O, WTproj, proj_b, P, 128, nullptr,nullptr,nullptr);
  gemm_mfma<4,2,1><<<dim3(1568,1),256,0,stream>>>(P, WTt1, tb1, Hq, 32, nullptr,nullptr,nullptr);
  gemm_mfma<1,4,2><<<dim3(1568,2),256,0,stream>>>(Hq, WTt2, tb2, Cb, 128, x, nullptr,nullptr);
  // ---- shifted-window spatial attention + S_Adapter ----
  ln_kernel<<<25088,256,0,stream>>>(Cb, n1g, n1b, Xn);
  gemm_mfma<4,4,0><<<dim3(1568,6),256,0,stream>>>(Xn, WTqkv, qkv_b, QKV, 384, nullptr,nullptr,nullptr);
  s_attn_kernel<<<2048,256,0,stream>>>(QKV, rpb, O);
  gemm_mfma<4,4,0><<<dim3(1568,2),256,0,stream>>>(O, WTproj, proj_b, P, 128, nullptr,nullptr,nullptr);
  gemm_mfma<4,2,1><<<dim3(1568,1),256,0,stream>>>(P, WTs1, sb1, Hq, 32, nullptr,nullptr,nullptr);
  gemm_mfma<1,4,3><<<dim3(1568,2),256,0,stream>>>(Hq, WTs2, sb2, out, 128, Cb, P, nullptr);
  // ---- MLP + MLP_Adapter ----
  ln_kernel<<<25088,256,0,stream>>>(out, n2g, n2b, Xn);
  gemm_mfma<4,2,1><<<dim3(1568,1),256,0,stream>>>(Xn, WTa1, ab1, Hq, 32, nullptr,nullptr,nullptr);
  gemm_mfma<1,4,5><<<dim3(1568,2),256,0,stream>>>(Hq, WTa2, ab2, Cb, 128, nullptr,nullptr,nullptr);
  gemm_mfma<4,4,1><<<dim3(1568,8),256,0,stream>>>(Xn, WTm1, mb1, QKV, 512, nullptr,nullptr,nullptr);
  gemm_mfma<16,4,4><<<dim3(1568,2),256,0,stream>>>(QKV, WTm2, mb2, out, 128, out, nullptr, Cb);
}

// Round 3
// 770.661 us; speedup vs baseline: 2.8911x; 1.1960x over previous
//
#include <hip/hip_runtime.h>

#define TOKS 100352   // BT*L = 32*3136
#define LDIM 3136     // H*W
#define SCALE_F 0.17677669529663687f  // 32^-0.5

typedef unsigned short u16;
typedef u16   u16x8 __attribute__((ext_vector_type(8)));
typedef short s16x8 __attribute__((ext_vector_type(8)));
typedef float f32x8 __attribute__((ext_vector_type(8)));
typedef float f32x4 __attribute__((ext_vector_type(4)));

__device__ __forceinline__ float bf2f(u16 u){ return __uint_as_float(((unsigned)u)<<16); }
__device__ __forceinline__ u16 f2bf(float f){
  unsigned u = __float_as_uint(f);
  return (u16)((u + 0x7FFFu + ((u>>16)&1u)) >> 16);   // RNE
}
__device__ __forceinline__ f32x8 ldbf8(const u16* p){
  u16x8 u = *(const u16x8*)p;
  f32x8 f;
  #pragma unroll
  for (int j=0;j<8;j++) f[j] = bf2f(u[j]);
  return f;
}
__device__ __forceinline__ u16x8 pack8(f32x8 v){
  u16x8 r;
  #pragma unroll
  for (int j=0;j<8;j++) r[j] = f2bf(v[j]);
  return r;
}
__device__ __forceinline__ float sum8(f32x8 a){
  return ((a[0]+a[1])+(a[2]+a[3]))+((a[4]+a[5])+(a[6]+a[7]));
}
__device__ __forceinline__ float gelu_f(float x){
  return 0.5f*x*(1.0f + erff(x*0.70710678118654752f));  // exact gelu
}

// ---------------- weight prep: f32 (K,N) -> bf16 transposed (N,K) ----------------
struct WSrc { const float* p[10]; };
__global__ __launch_bounds__(256) void prep_w(WSrc s, u16* __restrict__ dst){
  const int Ks[10]={128,128,128,512,128,32,128,32,128,32};
  const int Ns[10]={384,128,512,128,32,128,32,128,32,128};
  const int off[11]={0,49152,65536,131072,196608,200704,204800,208896,212992,217088,221184};
  int idx = blockIdx.x*256+threadIdx.x;
  int m=0;
  #pragma unroll
  for (int i=0;i<10;i++) if (idx>=off[i+1]) m=i+1;
  int e = idx-off[m];
  int K=Ks[m], Nn=Ns[m];
  int n=e/K, k=e-n*K;
  dst[idx] = f2bf(s.p[m][k*Nn+n]);
}

// ---------------- LayerNorm: one wave per token (C=128), bf16 out ----------------
__global__ __launch_bounds__(256) void ln_kernel(const float* __restrict__ x,
    const float* __restrict__ g, const float* __restrict__ bta, u16* __restrict__ out)
{
  int tok  = (int)((blockIdx.x*256u + threadIdx.x) >> 6);
  int lane = threadIdx.x & 63;
  const float* xr = x + (size_t)tok*128;
  float v0 = xr[lane], v1 = xr[lane+64];
  float s = v0+v1;
  #pragma unroll
  for (int o=32;o;o>>=1) s += __shfl_xor(s,o);
  float m = s*(1.0f/128.0f);
  float d0=v0-m, d1=v1-m;
  float q = d0*d0+d1*d1;
  #pragma unroll
  for (int o=32;o;o>>=1) q += __shfl_xor(q,o);
  float rs = rsqrtf(q*(1.0f/128.0f)+1e-5f);
  u16* orow = out + (size_t)tok*128;
  orow[lane]    = f2bf(d0*rs*g[lane]   + bta[lane]);
  orow[lane+64] = f2bf(d1*rs*g[lane+64]+ bta[lane+64]);
}

// ---- MFMA GEMM: (TOKS,K)bf16 @ WT(N,K)bf16 -> out, per-wave 16 tok x NT*16 cols ----
// EPI: 0=bf16 bias, 1=bf16 bias+gelu, 2=f32 bias+res1, 3=f32 bias+res1+resbf,
//      4=f32 bias+res1+0.5*ada, 5=f32 bias only
template<int KT, int NT, int EPI>
__global__ __launch_bounds__(256) void gemm_mfma(
    const u16* __restrict__ X, const u16* __restrict__ WT,
    const float* __restrict__ bias, void* outp, int N,
    const float* res1, const u16* __restrict__ resbf, const float* __restrict__ ada)
{
  constexpr int K = KT*32;
  const int tid = threadIdx.x;
  const int wv = tid>>6, lane = tid&63;
  const int lr = lane>>4, lc = lane&15;
  const size_t m0 = (size_t)blockIdx.x*64 + wv*16;
  const int n0 = blockIdx.y*(NT*16);
  f32x4 acc[NT];
  #pragma unroll
  for (int nt=0;nt<NT;nt++) acc[nt] = (f32x4){0.f,0.f,0.f,0.f};
  const u16* xa = X + (m0 + lc)*K + lr*8;
  const u16* wb = WT + ((size_t)(n0+lc))*K + lr*8;
  #pragma unroll 4
  for (int kt=0; kt<KT; kt++){
    s16x8 a = *(const s16x8*)(xa + kt*32);
    #pragma unroll
    for (int nt=0; nt<NT; nt++){
      s16x8 b = *(const s16x8*)(wb + (size_t)nt*16*K + kt*32);
      acc[nt] = __builtin_amdgcn_mfma_f32_16x16x32_bf16(a, b, acc[nt], 0,0,0);
    }
  }
  const int rowl = lr*4;
  #pragma unroll
  for (int nt=0; nt<NT; nt++){
    const int col = n0 + nt*16 + lc;
    const float bv = bias[col];
    #pragma unroll
    for (int r=0;r<4;r++){
      const size_t row = m0 + rowl + r;
      float v = acc[nt][r] + bv;
      if constexpr (EPI==1) v = gelu_f(v);
      if constexpr (EPI==0 || EPI==1){
        ((u16*)outp)[row*(size_t)N + col] = f2bf(v);
      } else {
        if constexpr (EPI==2) v += res1[row*128+col];
        if constexpr (EPI==3) v += res1[row*128+col] + bf2f(resbf[row*128+col]);
        if constexpr (EPI==4) v += res1[row*128+col] + 0.5f*ada[row*128+col];
        ((float*)outp)[row*128 + col] = v;
      }
    }
  }
}

// ---------------- temporal attention (T=8 per (b,l), 4 heads), bf16 out ----------------
__global__ __launch_bounds__(256) void t_attn_kernel(const u16* __restrict__ qkv,
    const float* __restrict__ tpb, u16* __restrict__ o)
{
  const int tid = threadIdx.x;
  const int li = tid>>5, h = (tid>>3)&3, t = tid&7;
  const int b = blockIdx.x/392, lt = blockIdx.x%392;
  const int l = lt*8+li;
  const size_t rowt = (size_t)(b*8+t)*LDIM + l;
  const u16* qp = qkv + rowt*384 + h*32;
  f32x8 q0 = ldbf8(qp)   *SCALE_F, q1 = ldbf8(qp+8) *SCALE_F,
        q2 = ldbf8(qp+16)*SCALE_F, q3 = ldbf8(qp+24)*SCALE_F;
  float s[8];
  #pragma unroll
  for (int t2=0;t2<8;t2++){
    const u16* kp = qkv + ((size_t)(b*8+t2)*LDIM + l)*384 + 128 + h*32;
    f32x8 d = q0*ldbf8(kp) + q1*ldbf8(kp+8) + q2*ldbf8(kp+16) + q3*ldbf8(kp+24);
    s[t2] = sum8(d) + tpb[(t-t2+7)*4 + h];
  }
  float m = s[0];
  #pragma unroll
  for (int t2=1;t2<8;t2++) m = fmaxf(m, s[t2]);
  float ssum = 0.f;
  #pragma unroll
  for (int t2=0;t2<8;t2++){ s[t2] = __expf(s[t2]-m); ssum += s[t2]; }
  const float inv = 1.0f/ssum;
  f32x8 o0={0,0,0,0,0,0,0,0}, o1={0,0,0,0,0,0,0,0},
        o2={0,0,0,0,0,0,0,0}, o3={0,0,0,0,0,0,0,0};
  #pragma unroll
  for (int t2=0;t2<8;t2++){
    const u16* vp = qkv + ((size_t)(b*8+t2)*LDIM + l)*384 + 256 + h*32;
    float aw = s[t2]*inv;
    o0 += aw*ldbf8(vp); o1 += aw*ldbf8(vp+8); o2 += aw*ldbf8(vp+16); o3 += aw*ldbf8(vp+24);
  }
  u16* op = o + rowt*128 + h*32;
  *(u16x8*)op      = pack8(o0); *(u16x8*)(op+8)  = pack8(o1);
  *(u16x8*)(op+16) = pack8(o2); *(u16x8*)(op+24) = pack8(o3);
}

// --------- MFMA shifted-window spatial attention ---------
// Block = 1 window (49 tokens, padded 64), 4 waves = 4 heads.
// S^T = mfma(K,Q) so lane holds P at fixed i=ti*16+lc -> lane-local softmax rows.
// PV A-frags assembled in-register via cvt-pack + __shfl (no P LDS round-trip).
__global__ __launch_bounds__(256,2) void s_attn_mfma(const u16* __restrict__ qkv,
    const float* __restrict__ rpb, u16* __restrict__ o)
{
  __shared__ u16 Qs[64][136];   // [i][c], stride 272B -> 2-way only
  __shared__ u16 Ks[64][136];
  __shared__ u16 Vt[128][72];   // [c][j], stride 144B -> 2-way only; j>=49 zeroed
  __shared__ float rpbL[676];
  __shared__ int rowL[49];
  __shared__ int codeL[49];
  const int tid = threadIdx.x;
  const int bidx = blockIdx.x;
  const int bt = bidx>>6, wh = (bidx>>3)&7, ww = bidx&7;
  if (tid < 49){
    int ph = tid/7, pwv = tid%7;
    int rh = wh*7+ph, rw = ww*7+pwv;
    int oh = rh+3; if (oh>=56) oh-=56;   // roll(-3)
    int ow = rw+3; if (ow>=56) ow-=56;
    rowL[tid] = bt*LDIM + oh*56 + ow;
    codeL[tid] = ((rh<49)?0:((rh<53)?1:2))*3 + ((rw<49)?0:((rw<53)?1:2));
  }
  for (int i2 = tid; i2 < 676; i2 += 256) rpbL[i2] = rpb[i2];
  for (int idx = tid; idx < 128*15; idx += 256){   // zero Vt cols 49..63
    int d = idx/15, jj = 49 + (idx - d*15);
    Vt[d][jj] = 0;
  }
  __syncthreads();   // rowL ready for staging
  #pragma unroll
  for (int it = 0; it < 10; it++){
    int idx = it*256 + tid;
    if (idx < 2352){
      int j = idx/48, s = idx - j*48;
      const u16* src = qkv + (size_t)rowL[j]*384 + s*8;
      u16x8 v = *(const u16x8*)src;
      if (s < 16)      *(u16x8*)&Qs[j][s*8] = v;
      else if (s < 32) *(u16x8*)&Ks[j][(s-16)*8] = v;
      else { int c0 = (s-32)*8;
        #pragma unroll
        for (int e=0;e<8;e++) Vt[c0+e][j] = v[e];
      }
    }
  }
  __syncthreads();

  const int h = tid>>6, lane = tid&63, lr = lane>>4, lc = lane&15;
  // ---- QK^T (swapped): sa[tj][ti] element r = S[i=ti*16+lc][j=tj*16+lr*4+r] ----
  s16x8 qf[4], kf[4];
  #pragma unroll
  for (int t=0;t<4;t++){
    qf[t] = *(const s16x8*)&Qs[t*16+lc][h*32+lr*8];
    kf[t] = *(const s16x8*)&Ks[t*16+lc][h*32+lr*8];
  }
  f32x4 sa[4][4];
  #pragma unroll
  for (int tj=0;tj<4;tj++){
    #pragma unroll
    for (int ti=0;ti<4;ti++)
      sa[tj][ti] = __builtin_amdgcn_mfma_f32_16x16x32_bf16(kf[tj], qf[ti], (f32x4){0.f,0.f,0.f,0.f}, 0,0,0);
  }
  // ---- bias + mask + exp (no max-subtract: scores bounded; masked -> ~0) ----
  int ihv[4], iwv[4], civ[4];
  #pragma unroll
  for (int ti=0;ti<4;ti++){
    int i = ti*16+lc; int im = (i<49)? i:48;
    int ih2 = (im*147)>>10; ihv[ti]=ih2; iwv[ti]=im-ih2*7; civ[ti]=codeL[im];
  }
  float rs[4] = {0.f,0.f,0.f,0.f};
  #pragma unroll
  for (int tj=0;tj<4;tj++){
    #pragma unroll
    for (int r=0;r<4;r++){
      int j = tj*16 + lr*4 + r;
      bool jv = (j<49);
      int jm = jv? j:48;
      int jh2 = (jm*147)>>10; int jw2 = jm - jh2*7; int cj = codeL[jm];
      #pragma unroll
      for (int ti=0;ti<4;ti++){
        float sv = sa[tj][ti][r]*SCALE_F
                 + rpbL[((ihv[ti]-jh2+6)*13 + (iwv[ti]-jw2+6))*4 + h];
        if (civ[ti] != cj) sv -= 100.f;
        float pv = jv ? __expf(sv) : 0.f;
        sa[tj][ti][r] = pv;
        rs[ti] += pv;
      }
    }
  }
  #pragma unroll
  for (int ti=0;ti<4;ti++){
    float t2 = rs[ti];
    t2 += __shfl_xor(t2, 16);
    t2 += __shfl_xor(t2, 32);
    rs[ti] = 1.0f/t2;
  }
  // ---- pack P*inv to bf16 pairs: lo=(r0,r1), hi=(r2,r3), j = tj*16+lr*4+{0..3} ----
  unsigned lo[4][4], hi[4][4];
  #pragma unroll
  for (int tj=0;tj<4;tj++){
    #pragma unroll
    for (int ti=0;ti<4;ti++){
      float inv = rs[ti];
      unsigned a0 = f2bf(sa[tj][ti][0]*inv), a1 = f2bf(sa[tj][ti][1]*inv);
      unsigned a2 = f2bf(sa[tj][ti][2]*inv), a3 = f2bf(sa[tj][ti][3]*inv);
      lo[tj][ti] = a0 | (a1<<16);
      hi[tj][ti] = a2 | (a3<<16);
    }
  }
  // ---- PV: O[i][d] = sum_j P[i][j] V[j][d]; A-frag needs P[mi*16+lc][kt*32+lr*8+e] ----
  f32x4 oa[4][2];
  #pragma unroll
  for (int mi=0;mi<4;mi++){ oa[mi][0]=(f32x4){0.f,0.f,0.f,0.f}; oa[mi][1]=(f32x4){0.f,0.f,0.f,0.f}; }
  const int srcA = lc + ((lane>>4)&1)*32;   // lane holding lr_src=2*(lr&1)
  const int srcB = srcA + 16;               // lr_src+1
  const bool hiHalf = (lr>=2);              // tj = 2kt + (lr>>1)
  #pragma unroll
  for (int kt=0;kt<2;kt++){
    s16x8 vf[2];
    #pragma unroll
    for (int nd=0;nd<2;nd++)
      vf[nd] = *(const s16x8*)&Vt[h*32 + nd*16 + lc][kt*32 + lr*8];
    #pragma unroll
    for (int mi=0;mi<4;mi++){
      unsigned wA0 = __shfl(lo[2*kt][mi],   srcA), wB0 = __shfl(lo[2*kt+1][mi], srcA);
      unsigned wA1 = __shfl(hi[2*kt][mi],   srcA), wB1 = __shfl(hi[2*kt+1][mi], srcA);
      unsigned wA2 = __shfl(lo[2*kt][mi],   srcB), wB2 = __shfl(lo[2*kt+1][mi], srcB);
      unsigned wA3 = __shfl(hi[2*kt][mi],   srcB), wB3 = __shfl(hi[2*kt+1][mi], srcB);
      union { unsigned u[4]; s16x8 v8; } cv;
      cv.u[0] = hiHalf? wB0 : wA0;
      cv.u[1] = hiHalf? wB1 : wA1;
      cv.u[2] = hiHalf? wB2 : wA2;
      cv.u[3] = hiHalf? wB3 : wA3;
      #pragma unroll
      for (int nd=0;nd<2;nd++)
        oa[mi][nd] = __builtin_amdgcn_mfma_f32_16x16x32_bf16(cv.v8, vf[nd], oa[mi][nd], 0,0,0);
    }
  }
  // ---- store: O[i = mi*16+lr*4+r][d = nd*16+lc] for i<49 ----
  #pragma unroll
  for (int mi=0;mi<4;mi++){
    #pragma unroll
    for (int r=0;r<4;r++){
      int i = mi*16 + lr*4 + r;
      if (i < 49){
        size_t orow = (size_t)rowL[i]*128 + h*32;
        o[orow + lc]      = f2bf(oa[mi][0][r]);
        o[orow + 16 + lc] = f2bf(oa[mi][1][r]);
      }
    }
  }
}

extern "C" void kernel_launch(void* const* d_in, const int* in_sizes, int n_in,
                              void* d_out, int out_size, void* d_ws, size_t ws_size,
                              hipStream_t stream)
{
  (void)in_sizes; (void)n_in; (void)out_size; (void)ws_size;
  const float* x      = (const float*)d_in[0];
  const float* qkv_w  = (const float*)d_in[1];
  const float* qkv_b  = (const float*)d_in[2];
  const float* proj_w = (const float*)d_in[3];
  const float* proj_b = (const float*)d_in[4];
  const float* rpb    = (const float*)d_in[5];
  const float* tpb    = (const float*)d_in[6];
  const float* n1g    = (const float*)d_in[7];
  const float* n1b    = (const float*)d_in[8];
  const float* n2g    = (const float*)d_in[9];
  const float* n2b    = (const float*)d_in[10];
  const float* mw1    = (const float*)d_in[11];
  const float* mb1    = (const float*)d_in[12];
  const float* mw2    = (const float*)d_in[13];
  const float* mb2    = (const float*)d_in[14];
  const float* sw1    = (const float*)d_in[15];
  const float* sb1    = (const float*)d_in[16];
  const float* sw2    = (const float*)d_in[17];
  const float* sb2    = (const float*)d_in[18];
  const float* tw1    = (const float*)d_in[19];
  const float* tb1    = (const float*)d_in[20];
  const float* tw2    = (const float*)d_in[21];
  const float* tb2    = (const float*)d_in[22];
  const float* aw1    = (const float*)d_in[23];
  const float* ab1    = (const float*)d_in[24];
  const float* aw2    = (const float*)d_in[25];
  const float* ab2    = (const float*)d_in[26];

  char* ws = (char*)d_ws;
  u16*   Xn  = (u16*)(ws);
  u16*   P   = Xn;                           // alias; disjoint lifetimes
  u16*   QKV = (u16*)(ws + 25690112ULL);     // also MLP hidden H
  u16*   O   = (u16*)(ws + 102760448ULL);
  u16*   Hq  = (u16*)(ws + 128450560ULL);
  float* Cb  = (float*)(ws + 134873088ULL);
  u16*   WT  = (u16*)(ws + 186253312ULL);
  float* out = (float*)d_out;

  const u16 *WTqkv=WT, *WTproj=WT+49152, *WTm1=WT+65536, *WTm2=WT+131072,
            *WTt1=WT+196608, *WTt2=WT+200704, *WTs1=WT+204800, *WTs2=WT+208896,
            *WTa1=WT+212992, *WTa2=WT+217088;

  WSrc srcs; srcs.p[0]=qkv_w; srcs.p[1]=proj_w; srcs.p[2]=mw1; srcs.p[3]=mw2;
  srcs.p[4]=tw1; srcs.p[5]=tw2; srcs.p[6]=sw1; srcs.p[7]=sw2; srcs.p[8]=aw1; srcs.p[9]=aw2;
  prep_w<<<864,256,0,stream>>>(srcs, WT);

  // ---- temporal attention + T_Adapter ----
  ln_kernel<<<25088,256,0,stream>>>(x, n1g, n1b, Xn);
  gemm_mfma<4,4,0><<<dim3(1568,6),256,0,stream>>>(Xn, WTqkv, qkv_b, QKV, 384, nullptr,nullptr,nullptr);
  t_attn_kernel<<<1568,256,0,stream>>>(QKV, tpb, O);
  gemm_mfma<4,4,0><<<dim3(1568,2),256,0,stream>>>(O, WTproj, proj_b, P, 128, nullptr,nullptr,nullptr);
  gemm_mfma<4,2,1><<<dim3(1568,1),256,0,stream>>>(P, WTt1, tb1, Hq, 32, nullptr,nullptr,nullptr);
  gemm_mfma<1,4,2><<<dim3(1568,2),256,0,stream>>>(Hq, WTt2, tb2, Cb, 128, x, nullptr,nullptr);
  // ---- shifted-window spatial attention + S_Adapter ----
  ln_kernel<<<25088,256,0,stream>>>(Cb, n1g, n1b, Xn);
  gemm_mfma<4,4,0><<<dim3(1568,6),256,0,stream>>>(Xn, WTqkv, qkv_b, QKV, 384, nullptr,nullptr,nullptr);
  s_attn_mfma<<<2048,256,0,stream>>>(QKV, rpb, O);
  gemm_mfma<4,4,0><<<dim3(1568,2),256,0,stream>>>(O, WTproj, proj_b, P, 128, nullptr,nullptr,nullptr);
  gemm_mfma<4,2,1><<<dim3(1568,1),256,0,stream>>>(P, WTs1, sb1, Hq, 32, nullptr,nullptr,nullptr);
  gemm_mfma<1,4,3><<<dim3(1568,2),256,0,stream>>>(Hq, WTs2, sb2, out, 128, Cb, P, nullptr);
  // ---- MLP + MLP_Adapter ----
  ln_kernel<<<25088,256,0,stream>>>(out, n2g, n2b, Xn);
  gemm_mfma<4,2,1><<<dim3(1568,1),256,0,stream>>>(Xn, WTa1, ab1, Hq, 32, nullptr,nullptr,nullptr);
  gemm_mfma<1,4,5><<<dim3(1568,2),256,0,stream>>>(Hq, WTa2, ab2, Cb, 128, nullptr,nullptr,nullptr);
  gemm_mfma<4,4,1><<<dim3(1568,8),256,0,stream>>>(Xn, WTm1, mb1, QKV, 512, nullptr,nullptr,nullptr);
  gemm_mfma<16,4,4><<<dim3(1568,2),256,0,stream>>>(QKV, WTm2, mb2, out, 128, out, nullptr, Cb);
}

// Round 4
// 482.297 us; speedup vs baseline: 4.6197x; 1.5979x over previous
//
#include <hip/hip_runtime.h>

#define TOKS 100352   // BT*L = 32*3136
#define LDIM 3136     // H*W
#define SCALE_F 0.17677669529663687f  // 32^-0.5

typedef unsigned short u16;
typedef u16   u16x8 __attribute__((ext_vector_type(8)));
typedef short s16x8 __attribute__((ext_vector_type(8)));
typedef float f32x8 __attribute__((ext_vector_type(8)));
typedef float f32x4 __attribute__((ext_vector_type(4)));

__device__ __forceinline__ float bf2f(u16 u){ return __uint_as_float(((unsigned)u)<<16); }
__device__ __forceinline__ u16 f2bf(float f){
  unsigned u = __float_as_uint(f);
  return (u16)((u + 0x7FFFu + ((u>>16)&1u)) >> 16);   // RNE
}
__device__ __forceinline__ f32x8 ldbf8(const u16* p){
  u16x8 u = *(const u16x8*)p;
  f32x8 f;
  #pragma unroll
  for (int j=0;j<8;j++) f[j] = bf2f(u[j]);
  return f;
}
__device__ __forceinline__ u16x8 pack8(f32x8 v){
  u16x8 r;
  #pragma unroll
  for (int j=0;j<8;j++) r[j] = f2bf(v[j]);
  return r;
}
__device__ __forceinline__ float sum8(f32x8 a){
  return ((a[0]+a[1])+(a[2]+a[3]))+((a[4]+a[5])+(a[6]+a[7]));
}
__device__ __forceinline__ float gelu_f(float x){
  return 0.5f*x*(1.0f + erff(x*0.70710678118654752f));  // exact gelu
}

// ---------------- weight prep: f32 (K,N) -> bf16 transposed (N,K) ----------------
struct WSrc { const float* p[10]; };
__global__ __launch_bounds__(256) void prep_w(WSrc s, u16* __restrict__ dst){
  const int Ks[10]={128,128,128,512,128,32,128,32,128,32};
  const int Ns[10]={384,128,512,128,32,128,32,128,32,128};
  const int off[11]={0,49152,65536,131072,196608,200704,204800,208896,212992,217088,221184};
  int idx = blockIdx.x*256+threadIdx.x;
  int m=0;
  #pragma unroll
  for (int i=0;i<10;i++) if (idx>=off[i+1]) m=i+1;
  int e = idx-off[m];
  int K=Ks[m], Nn=Ns[m];
  int n=e/K, k=e-n*K;
  dst[idx] = f2bf(s.p[m][k*Nn+n]);
}

// ---------------- LayerNorm: one wave per token (C=128), bf16 out ----------------
__global__ __launch_bounds__(256) void ln_kernel(const float* __restrict__ x,
    const float* __restrict__ g, const float* __restrict__ bta, u16* __restrict__ out)
{
  int tok  = (int)((blockIdx.x*256u + threadIdx.x) >> 6);
  int lane = threadIdx.x & 63;
  const float* xr = x + (size_t)tok*128;
  float v0 = xr[lane], v1 = xr[lane+64];
  float s = v0+v1;
  #pragma unroll
  for (int o=32;o;o>>=1) s += __shfl_xor(s,o);
  float m = s*(1.0f/128.0f);
  float d0=v0-m, d1=v1-m;
  float q = d0*d0+d1*d1;
  #pragma unroll
  for (int o=32;o;o>>=1) q += __shfl_xor(q,o);
  float rs = rsqrtf(q*(1.0f/128.0f)+1e-5f);
  u16* orow = out + (size_t)tok*128;
  orow[lane]    = f2bf(d0*rs*g[lane]   + bta[lane]);
  orow[lane+64] = f2bf(d1*rs*g[lane+64]+ bta[lane+64]);
}

// ======== Tiled MFMA GEMM: 128-row block, LDS-staged, XOR-swizzled ========
// X (TOKS, KCH*128) bf16; WT (N, KCH*128) bf16. Block computes rows [row0,row0+128)
// for all N (looped in 128-col tiles with A resident). 4 waves 2x2, 64x64 each.
// Swizzle: data (row, kblk) lives at 16B-slot row*16 + (kblk ^ (row&7)).
// EPI: 0 = bf16 bias; 1 = bf16 bias+gelu; 4 = f32 bias + res1 + 0.5*ada (in-place ok)
template<int KCH, int NTC, int EPI>
__global__ __launch_bounds__(256,2) void gemm_tile(
    const u16* __restrict__ X, const u16* __restrict__ WT,
    const float* __restrict__ bias, void* outp, int N,
    const float* res1, const float* ada)
{
  constexpr int KTOT = KCH*128;
  __shared__ u16 As[128*128];
  __shared__ u16 Bs[128*128];
  const int tid = threadIdx.x;
  const int wv = tid>>6, lane = tid&63, lr = lane>>4, lc = lane&15;
  const int wr = wv>>1, wc = wv&1;
  const size_t row0 = (size_t)blockIdx.x*128;
  const int s_r = tid>>4, s_kb = tid&15;   // staging: 16 rows/iter-step of 16 blocks

  f32x4 acc[4][4];
  #pragma unroll
  for (int mi=0;mi<4;mi++)
    #pragma unroll
    for (int nj=0;nj<4;nj++) acc[mi][nj] = (f32x4){0.f,0.f,0.f,0.f};

  for (int kc=0; kc<KCH; kc++){
    for (int nt=0; nt<NTC; nt++){
      if (kc+nt > 0) __syncthreads();   // prior compute done before overwrite
      if (nt == 0){
        #pragma unroll
        for (int it=0; it<8; it++){
          int r = it*16 + s_r;
          u16x8 v = *(const u16x8*)&X[(row0+r)*KTOT + kc*128 + s_kb*8];
          *(u16x8*)&As[r*128 + ((s_kb ^ (r&7))*8)] = v;
        }
      }
      {
        const u16* Wb = WT + (size_t)(nt*128)*KTOT + kc*128;
        #pragma unroll
        for (int it=0; it<8; it++){
          int c = it*16 + s_r;
          u16x8 v = *(const u16x8*)&Wb[(size_t)c*KTOT + s_kb*8];
          *(u16x8*)&Bs[c*128 + ((s_kb ^ (c&7))*8)] = v;
        }
      }
      __syncthreads();
      #pragma unroll
      for (int kt=0; kt<4; kt++){
        s16x8 af[4], bfr[4];
        #pragma unroll
        for (int mi=0;mi<4;mi++){
          int row = wr*64 + mi*16 + lc;
          af[mi] = *(const s16x8*)&As[row*128 + (((kt*4+lr) ^ (lc&7))*8)];
        }
        #pragma unroll
        for (int nj=0;nj<4;nj++){
          int col = wc*64 + nj*16 + lc;
          bfr[nj] = *(const s16x8*)&Bs[col*128 + (((kt*4+lr) ^ (lc&7))*8)];
        }
        #pragma unroll
        for (int mi=0;mi<4;mi++)
          #pragma unroll
          for (int nj=0;nj<4;nj++)
            acc[mi][nj] = __builtin_amdgcn_mfma_f32_16x16x32_bf16(af[mi], bfr[nj], acc[mi][nj], 0,0,0);
      }
      if (KCH==1){   // K complete -> epilogue for this n-tile, then reset acc
        #pragma unroll
        for (int mi=0;mi<4;mi++){
          #pragma unroll
          for (int nj=0;nj<4;nj++){
            const int col = nt*128 + wc*64 + nj*16 + lc;
            const float bv = bias[col];
            #pragma unroll
            for (int r=0;r<4;r++){
              const size_t row = row0 + wr*64 + mi*16 + lr*4 + r;
              float v = acc[mi][nj][r] + bv;
              if constexpr (EPI==1) v = gelu_f(v);
              ((u16*)outp)[row*(size_t)N + col] = f2bf(v);
            }
            acc[mi][nj] = (f32x4){0.f,0.f,0.f,0.f};
          }
        }
      }
    }
  }
  if (KCH>1){   // single n-tile, K accumulated across chunks
    #pragma unroll
    for (int mi=0;mi<4;mi++){
      #pragma unroll
      for (int nj=0;nj<4;nj++){
        const int col = wc*64 + nj*16 + lc;
        const float bv = bias[col];
        #pragma unroll
        for (int r=0;r<4;r++){
          const size_t row = row0 + wr*64 + mi*16 + lr*4 + r;
          float v = acc[mi][nj][r] + bv;
          if constexpr (EPI==4) v += res1[row*128+col] + 0.5f*ada[row*128+col];
          ((float*)outp)[row*128 + col] = v;
        }
      }
    }
  }
}

// ---- direct MFMA GEMM (small adapters): per-wave 16 tok x NT*16 cols ----
// EPI: 0=bf16 bias, 1=bf16 bias+gelu, 2=f32 bias+res1, 3=f32 bias+res1+resbf,
//      4=f32 bias+res1+0.5*ada, 5=f32 bias only
template<int KT, int NT, int EPI>
__global__ __launch_bounds__(256) void gemm_mfma(
    const u16* __restrict__ X, const u16* __restrict__ WT,
    const float* __restrict__ bias, void* outp, int N,
    const float* res1, const u16* __restrict__ resbf, const float* __restrict__ ada)
{
  constexpr int K = KT*32;
  const int tid = threadIdx.x;
  const int wv = tid>>6, lane = tid&63;
  const int lr = lane>>4, lc = lane&15;
  const size_t m0 = (size_t)blockIdx.x*64 + wv*16;
  const int n0 = blockIdx.y*(NT*16);
  f32x4 acc[NT];
  #pragma unroll
  for (int nt=0;nt<NT;nt++) acc[nt] = (f32x4){0.f,0.f,0.f,0.f};
  const u16* xa = X + (m0 + lc)*K + lr*8;
  const u16* wb = WT + ((size_t)(n0+lc))*K + lr*8;
  #pragma unroll 4
  for (int kt=0; kt<KT; kt++){
    s16x8 a = *(const s16x8*)(xa + kt*32);
    #pragma unroll
    for (int nt=0; nt<NT; nt++){
      s16x8 b = *(const s16x8*)(wb + (size_t)nt*16*K + kt*32);
      acc[nt] = __builtin_amdgcn_mfma_f32_16x16x32_bf16(a, b, acc[nt], 0,0,0);
    }
  }
  const int rowl = lr*4;
  #pragma unroll
  for (int nt=0; nt<NT; nt++){
    const int col = n0 + nt*16 + lc;
    const float bv = bias[col];
    #pragma unroll
    for (int r=0;r<4;r++){
      const size_t row = m0 + rowl + r;
      float v = acc[nt][r] + bv;
      if constexpr (EPI==1) v = gelu_f(v);
      if constexpr (EPI==0 || EPI==1){
        ((u16*)outp)[row*(size_t)N + col] = f2bf(v);
      } else {
        if constexpr (EPI==2) v += res1[row*128+col];
        if constexpr (EPI==3) v += res1[row*128+col] + bf2f(resbf[row*128+col]);
        if constexpr (EPI==4) v += res1[row*128+col] + 0.5f*ada[row*128+col];
        ((float*)outp)[row*128 + col] = v;
      }
    }
  }
}

// ---------------- temporal attention (T=8 per (b,l), 4 heads), bf16 out ----------------
__global__ __launch_bounds__(256) void t_attn_kernel(const u16* __restrict__ qkv,
    const float* __restrict__ tpb, u16* __restrict__ o)
{
  const int tid = threadIdx.x;
  const int li = tid>>5, h = (tid>>3)&3, t = tid&7;
  const int b = blockIdx.x/392, lt = blockIdx.x%392;
  const int l = lt*8+li;
  const size_t rowt = (size_t)(b*8+t)*LDIM + l;
  const u16* qp = qkv + rowt*384 + h*32;
  f32x8 q0 = ldbf8(qp)   *SCALE_F, q1 = ldbf8(qp+8) *SCALE_F,
        q2 = ldbf8(qp+16)*SCALE_F, q3 = ldbf8(qp+24)*SCALE_F;
  float s[8];
  #pragma unroll
  for (int t2=0;t2<8;t2++){
    const u16* kp = qkv + ((size_t)(b*8+t2)*LDIM + l)*384 + 128 + h*32;
    f32x8 d = q0*ldbf8(kp) + q1*ldbf8(kp+8) + q2*ldbf8(kp+16) + q3*ldbf8(kp+24);
    s[t2] = sum8(d) + tpb[(t-t2+7)*4 + h];
  }
  float m = s[0];
  #pragma unroll
  for (int t2=1;t2<8;t2++) m = fmaxf(m, s[t2]);
  float ssum = 0.f;
  #pragma unroll
  for (int t2=0;t2<8;t2++){ s[t2] = __expf(s[t2]-m); ssum += s[t2]; }
  const float inv = 1.0f/ssum;
  f32x8 o0={0,0,0,0,0,0,0,0}, o1={0,0,0,0,0,0,0,0},
        o2={0,0,0,0,0,0,0,0}, o3={0,0,0,0,0,0,0,0};
  #pragma unroll
  for (int t2=0;t2<8;t2++){
    const u16* vp = qkv + ((size_t)(b*8+t2)*LDIM + l)*384 + 256 + h*32;
    float aw = s[t2]*inv;
    o0 += aw*ldbf8(vp); o1 += aw*ldbf8(vp+8); o2 += aw*ldbf8(vp+16); o3 += aw*ldbf8(vp+24);
  }
  u16* op = o + rowt*128 + h*32;
  *(u16x8*)op      = pack8(o0); *(u16x8*)(op+8)  = pack8(o1);
  *(u16x8*)(op+16) = pack8(o2); *(u16x8*)(op+24) = pack8(o3);
}

// --------- MFMA shifted-window spatial attention ---------
__global__ __launch_bounds__(256,2) void s_attn_mfma(const u16* __restrict__ qkv,
    const float* __restrict__ rpb, u16* __restrict__ o)
{
  __shared__ u16 Qs[64][136];
  __shared__ u16 Ks[64][136];
  __shared__ u16 Vt[128][72];
  __shared__ float rpbL[676];
  __shared__ int rowL[49];
  __shared__ int codeL[49];
  const int tid = threadIdx.x;
  const int bidx = blockIdx.x;
  const int bt = bidx>>6, wh = (bidx>>3)&7, ww = bidx&7;
  if (tid < 49){
    int ph = tid/7, pwv = tid%7;
    int rh = wh*7+ph, rw = ww*7+pwv;
    int oh = rh+3; if (oh>=56) oh-=56;   // roll(-3)
    int ow = rw+3; if (ow>=56) ow-=56;
    rowL[tid] = bt*LDIM + oh*56 + ow;
    codeL[tid] = ((rh<49)?0:((rh<53)?1:2))*3 + ((rw<49)?0:((rw<53)?1:2));
  }
  for (int i2 = tid; i2 < 676; i2 += 256) rpbL[i2] = rpb[i2];
  for (int idx = tid; idx < 128*15; idx += 256){
    int d = idx/15, jj = 49 + (idx - d*15);
    Vt[d][jj] = 0;
  }
  __syncthreads();
  #pragma unroll
  for (int it = 0; it < 10; it++){
    int idx = it*256 + tid;
    if (idx < 2352){
      int j = idx/48, s = idx - j*48;
      const u16* src = qkv + (size_t)rowL[j]*384 + s*8;
      u16x8 v = *(const u16x8*)src;
      if (s < 16)      *(u16x8*)&Qs[j][s*8] = v;
      else if (s < 32) *(u16x8*)&Ks[j][(s-16)*8] = v;
      else { int c0 = (s-32)*8;
        #pragma unroll
        for (int e=0;e<8;e++) Vt[c0+e][j] = v[e];
      }
    }
  }
  __syncthreads();

  const int h = tid>>6, lane = tid&63, lr = lane>>4, lc = lane&15;
  s16x8 qf[4], kf[4];
  #pragma unroll
  for (int t=0;t<4;t++){
    qf[t] = *(const s16x8*)&Qs[t*16+lc][h*32+lr*8];
    kf[t] = *(const s16x8*)&Ks[t*16+lc][h*32+lr*8];
  }
  f32x4 sa[4][4];
  #pragma unroll
  for (int tj=0;tj<4;tj++){
    #pragma unroll
    for (int ti=0;ti<4;ti++)
      sa[tj][ti] = __builtin_amdgcn_mfma_f32_16x16x32_bf16(kf[tj], qf[ti], (f32x4){0.f,0.f,0.f,0.f}, 0,0,0);
  }
  int ihv[4], iwv[4], civ[4];
  #pragma unroll
  for (int ti=0;ti<4;ti++){
    int i = ti*16+lc; int im = (i<49)? i:48;
    int ih2 = (im*147)>>10; ihv[ti]=ih2; iwv[ti]=im-ih2*7; civ[ti]=codeL[im];
  }
  float rs[4] = {0.f,0.f,0.f,0.f};
  #pragma unroll
  for (int tj=0;tj<4;tj++){
    #pragma unroll
    for (int r=0;r<4;r++){
      int j = tj*16 + lr*4 + r;
      bool jv = (j<49);
      int jm = jv? j:48;
      int jh2 = (jm*147)>>10; int jw2 = jm - jh2*7; int cj = codeL[jm];
      #pragma unroll
      for (int ti=0;ti<4;ti++){
        float sv = sa[tj][ti][r]*SCALE_F
                 + rpbL[((ihv[ti]-jh2+6)*13 + (iwv[ti]-jw2+6))*4 + h];
        if (civ[ti] != cj) sv -= 100.f;
        float pv = jv ? __expf(sv) : 0.f;
        sa[tj][ti][r] = pv;
        rs[ti] += pv;
      }
    }
  }
  #pragma unroll
  for (int ti=0;ti<4;ti++){
    float t2 = rs[ti];
    t2 += __shfl_xor(t2, 16);
    t2 += __shfl_xor(t2, 32);
    rs[ti] = 1.0f/t2;
  }
  unsigned lo[4][4], hi[4][4];
  #pragma unroll
  for (int tj=0;tj<4;tj++){
    #pragma unroll
    for (int ti=0;ti<4;ti++){
      float inv = rs[ti];
      unsigned a0 = f2bf(sa[tj][ti][0]*inv), a1 = f2bf(sa[tj][ti][1]*inv);
      unsigned a2 = f2bf(sa[tj][ti][2]*inv), a3 = f2bf(sa[tj][ti][3]*inv);
      lo[tj][ti] = a0 | (a1<<16);
      hi[tj][ti] = a2 | (a3<<16);
    }
  }
  f32x4 oa[4][2];
  #pragma unroll
  for (int mi=0;mi<4;mi++){ oa[mi][0]=(f32x4){0.f,0.f,0.f,0.f}; oa[mi][1]=(f32x4){0.f,0.f,0.f,0.f}; }
  const int srcA = lc + ((lane>>4)&1)*32;
  const int srcB = srcA + 16;
  const bool hiHalf = (lr>=2);
  #pragma unroll
  for (int kt=0;kt<2;kt++){
    s16x8 vf[2];
    #pragma unroll
    for (int nd=0;nd<2;nd++)
      vf[nd] = *(const s16x8*)&Vt[h*32 + nd*16 + lc][kt*32 + lr*8];
    #pragma unroll
    for (int mi=0;mi<4;mi++){
      unsigned wA0 = __shfl(lo[2*kt][mi],   srcA), wB0 = __shfl(lo[2*kt+1][mi], srcA);
      unsigned wA1 = __shfl(hi[2*kt][mi],   srcA), wB1 = __shfl(hi[2*kt+1][mi], srcA);
      unsigned wA2 = __shfl(lo[2*kt][mi],   srcB), wB2 = __shfl(lo[2*kt+1][mi], srcB);
      unsigned wA3 = __shfl(hi[2*kt][mi],   srcB), wB3 = __shfl(hi[2*kt+1][mi], srcB);
      union { unsigned u[4]; s16x8 v8; } cv;
      cv.u[0] = hiHalf? wB0 : wA0;
      cv.u[1] = hiHalf? wB1 : wA1;
      cv.u[2] = hiHalf? wB2 : wA2;
      cv.u[3] = hiHalf? wB3 : wA3;
      #pragma unroll
      for (int nd=0;nd<2;nd++)
        oa[mi][nd] = __builtin_amdgcn_mfma_f32_16x16x32_bf16(cv.v8, vf[nd], oa[mi][nd], 0,0,0);
    }
  }
  #pragma unroll
  for (int mi=0;mi<4;mi++){
    #pragma unroll
    for (int r=0;r<4;r++){
      int i = mi*16 + lr*4 + r;
      if (i < 49){
        size_t orow = (size_t)rowL[i]*128 + h*32;
        o[orow + lc]      = f2bf(oa[mi][0][r]);
        o[orow + 16 + lc] = f2bf(oa[mi][1][r]);
      }
    }
  }
}

extern "C" void kernel_launch(void* const* d_in, const int* in_sizes, int n_in,
                              void* d_out, int out_size, void* d_ws, size_t ws_size,
                              hipStream_t stream)
{
  (void)in_sizes; (void)n_in; (void)out_size; (void)ws_size;
  const float* x      = (const float*)d_in[0];
  const float* qkv_w  = (const float*)d_in[1];
  const float* qkv_b  = (const float*)d_in[2];
  const float* proj_w = (const float*)d_in[3];
  const float* proj_b = (const float*)d_in[4];
  const float* rpb    = (const float*)d_in[5];
  const float* tpb    = (const float*)d_in[6];
  const float* n1g    = (const float*)d_in[7];
  const float* n1b    = (const float*)d_in[8];
  const float* n2g    = (const float*)d_in[9];
  const float* n2b    = (const float*)d_in[10];
  const float* mw1    = (const float*)d_in[11];
  const float* mb1    = (const float*)d_in[12];
  const float* mw2    = (const float*)d_in[13];
  const float* mb2    = (const float*)d_in[14];
  const float* sw1    = (const float*)d_in[15];
  const float* sb1    = (const float*)d_in[16];
  const float* sw2    = (const float*)d_in[17];
  const float* sb2    = (const float*)d_in[18];
  const float* tw1    = (const float*)d_in[19];
  const float* tb1    = (const float*)d_in[20];
  const float* tw2    = (const float*)d_in[21];
  const float* tb2    = (const float*)d_in[22];
  const float* aw1    = (const float*)d_in[23];
  const float* ab1    = (const float*)d_in[24];
  const float* aw2    = (const float*)d_in[25];
  const float* ab2    = (const float*)d_in[26];

  char* ws = (char*)d_ws;
  u16*   Xn  = (u16*)(ws);
  u16*   P   = Xn;                           // alias; disjoint lifetimes
  u16*   QKV = (u16*)(ws + 25690112ULL);     // also MLP hidden H
  u16*   O   = (u16*)(ws + 102760448ULL);
  u16*   Hq  = (u16*)(ws + 128450560ULL);
  float* Cb  = (float*)(ws + 134873088ULL);
  u16*   WT  = (u16*)(ws + 186253312ULL);
  float* out = (float*)d_out;

  const u16 *WTqkv=WT, *WTproj=WT+49152, *WTm1=WT+65536, *WTm2=WT+131072,
            *WTt1=WT+196608, *WTt2=WT+200704, *WTs1=WT+204800, *WTs2=WT+208896,
            *WTa1=WT+212992, *WTa2=WT+217088;

  WSrc srcs; srcs.p[0]=qkv_w; srcs.p[1]=proj_w; srcs.p[2]=mw1; srcs.p[3]=mw2;
  srcs.p[4]=tw1; srcs.p[5]=tw2; srcs.p[6]=sw1; srcs.p[7]=sw2; srcs.p[8]=aw1; srcs.p[9]=aw2;
  prep_w<<<864,256,0,stream>>>(srcs, WT);

  // ---- temporal attention + T_Adapter ----
  ln_kernel<<<25088,256,0,stream>>>(x, n1g, n1b, Xn);
  gemm_tile<1,3,0><<<784,256,0,stream>>>(Xn, WTqkv, qkv_b, QKV, 384, nullptr,nullptr);
  t_attn_kernel<<<1568,256,0,stream>>>(QKV, tpb, O);
  gemm_tile<1,1,0><<<784,256,0,stream>>>(O, WTproj, proj_b, P, 128, nullptr,nullptr);
  gemm_mfma<4,2,1><<<dim3(1568,1),256,0,stream>>>(P, WTt1, tb1, Hq, 32, nullptr,nullptr,nullptr);
  gemm_mfma<1,4,2><<<dim3(1568,2),256,0,stream>>>(Hq, WTt2, tb2, Cb, 128, x, nullptr,nullptr);
  // ---- shifted-window spatial attention + S_Adapter ----
  ln_kernel<<<25088,256,0,stream>>>(Cb, n1g, n1b, Xn);
  gemm_tile<1,3,0><<<784,256,0,stream>>>(Xn, WTqkv, qkv_b, QKV, 384, nullptr,nullptr);
  s_attn_mfma<<<2048,256,0,stream>>>(QKV, rpb, O);
  gemm_tile<1,1,0><<<784,256,0,stream>>>(O, WTproj, proj_b, P, 128, nullptr,nullptr);
  gemm_mfma<4,2,1><<<dim3(1568,1),256,0,stream>>>(P, WTs1, sb1, Hq, 32, nullptr,nullptr,nullptr);
  gemm_mfma<1,4,3><<<dim3(1568,2),256,0,stream>>>(Hq, WTs2, sb2, out, 128, Cb, P, nullptr);
  // ---- MLP + MLP_Adapter ----
  ln_kernel<<<25088,256,0,stream>>>(out, n2g, n2b, Xn);
  gemm_mfma<4,2,1><<<dim3(1568,1),256,0,stream>>>(Xn, WTa1, ab1, Hq, 32, nullptr,nullptr,nullptr);
  gemm_mfma<1,4,5><<<dim3(1568,2),256,0,stream>>>(Hq, WTa2, ab2, Cb, 128, nullptr,nullptr,nullptr);
  gemm_tile<1,4,1><<<784,256,0,stream>>>(Xn, WTm1, mb1, QKV, 512, nullptr,nullptr);
  gemm_tile<4,1,4><<<784,256,0,stream>>>(QKV, WTm2, mb2, out, 128, out, Cb);
}